// Round 6
// baseline (1148.570 us; speedup 1.0000x reference)
//
#include <hip/hip_runtime.h>

#define B 8
#define N 8192
#define S 1024
#define NS 32
constexpr float BN_EPS = 1e-5f;

typedef float v2f __attribute__((ext_vector_type(2)));

// DPP-based full-wave (64-lane) f32 max; result valid in lane 63.
__device__ __forceinline__ float wave_max_to_lane63(float x) {
  int v = __float_as_int(x);
#define DPP_MAX(ctrl)                                                     \
  v = __float_as_int(fmaxf(__int_as_float(v),                             \
      __int_as_float(__builtin_amdgcn_update_dpp(v, v, (ctrl), 0xf, 0xf, \
                                                 false))))
  DPP_MAX(0x111);  // row_shr:1
  DPP_MAX(0x112);  // row_shr:2
  DPP_MAX(0x114);  // row_shr:4
  DPP_MAX(0x118);  // row_shr:8  -> lane15/31/47/63 hold row maxima
  DPP_MAX(0x142);  // row_bcast:15 -> lane31 = rows0-1, lane63 = rows2-3
  DPP_MAX(0x143);  // row_bcast:31 -> lane63 = all 64
#undef DPP_MAX
  return __int_as_float(v);
}

// One step of a u64 (hi,lo) max with a DPP row_shr shuffle; ctrl is a literal.
#define DPP_U64MAX_STEP(ctrl)                                                  \
  do {                                                                         \
    int shi = __builtin_amdgcn_update_dpp(hi, hi, (ctrl), 0xf, 0xf, false);    \
    int slo = __builtin_amdgcn_update_dpp(lo, lo, (ctrl), 0xf, 0xf, false);    \
    bool gt = ((unsigned)shi > (unsigned)hi) ||                                \
              ((unsigned)shi == (unsigned)hi && (unsigned)slo > (unsigned)lo); \
    hi = gt ? shi : hi;                                                        \
    lo = gt ? slo : lo;                                                        \
  } while (0)

// ---------------------------------------------------------------------------
// K1: furthest point sampling. One block per batch; 512 threads, 16 pts/thread
// register-resident (waves_per_eu(2,2) -> 88 VGPRs, no spill, verified R4).
// R5/R6 changes:
//  - NO global stores inside the round loop: winner coords accumulate in
//    s_ctr (LDS) and new_xyz is written once, coalesced, after the loop.
//    R4's per-round t==0 global store forced a vmcnt(0) drain before every
//    s_barrier (compiler inserts full waitcnt before barrier) -> ~300-500 cy
//    of HBM-store latency on the round critical path.
//  - Cross-wave reduce: each lane reads wave key (lane&7) (one ds_read_b64),
//    3-step DPP row_shr u64-max into lane 7, one readlane -> uniform winner.
// Exact contract-off fp32 distance math -> argmax selections match the NumPy
// reference bit-for-bit; ties -> smallest index via (8191-idx) key low word.
// ---------------------------------------------------------------------------
#define FPS_T 512

__global__ void __attribute__((amdgpu_flat_work_group_size(FPS_T, FPS_T),
                               amdgpu_waves_per_eu(2, 2)))
k_fps(const float* __restrict__ xyz, float* __restrict__ new_xyz) {
#pragma clang fp contract(off)
  extern __shared__ float s_xyz[];  // N*3 floats = 96 KB
  __shared__ alignas(16) float s_ctr[S * 3];       // chosen centers, 12 KB
  __shared__ unsigned long long s_red[2][8];
  const int b = blockIdx.x;
  const int t = threadIdx.x;
  const int lane = t & 63;
  const int w = t >> 6;
  const float* base = xyz + (size_t)b * N * 3;
  v2f X[8], Y[8], Z[8], D[8];
  const int p0 = t * 16;
  {
    // 16 pts * 3 floats = 12 float4 loads, 16B-aligned (t*192 bytes);
    // mirrored into LDS for the per-round winner-coords broadcast.
    const float4* src = (const float4*)(base + (size_t)p0 * 3);
    float4* dst = (float4*)(s_xyz + (size_t)p0 * 3);
    float buf[48];
#pragma unroll
    for (int i = 0; i < 12; ++i) {
      float4 v = src[i];
      dst[i] = v;
      buf[4 * i + 0] = v.x; buf[4 * i + 1] = v.y;
      buf[4 * i + 2] = v.z; buf[4 * i + 3] = v.w;
    }
#pragma unroll
    for (int i = 0; i < 8; ++i) {
      X[i] = (v2f){buf[6 * i + 0], buf[6 * i + 3]};
      Y[i] = (v2f){buf[6 * i + 1], buf[6 * i + 4]};
      Z[i] = (v2f){buf[6 * i + 2], buf[6 * i + 5]};
      D[i] = (v2f){3.4e38f, 3.4e38f};  // ref init +inf; min(inf,d)=d, d<=3
    }
  }
  float lx = base[0], ly = base[1], lz = base[2];  // start index 0
  if (t == 0) {
    s_ctr[0] = lx; s_ctr[1] = ly; s_ctr[2] = lz;
  }
  for (int r = 1; r < S; ++r) {
    v2f lx2 = lx, ly2 = ly, lz2 = lz;
    // exact: d = ((dx*dx)+(dy*dy))+(dz*dz), contraction off; pk ops round
    // identically to scalar per lane-half.
#pragma unroll
    for (int i = 0; i < 8; ++i) {
      v2f dx = X[i] - lx2, dy = Y[i] - ly2, dz = Z[i] - lz2;
      v2f d = (dx * dx + dy * dy) + dz * dz;
      D[i].x = fminf(D[i].x, d.x);
      D[i].y = fminf(D[i].y, d.y);
    }
    float m = fmaxf(D[0].x, D[0].y);
#pragma unroll
    for (int i = 1; i < 8; ++i) m = fmaxf(m, fmaxf(D[i].x, D[i].y));
    int li = 0;
#pragma unroll
    for (int i = 7; i >= 0; --i) {  // descending -> smallest index wins
      if (D[i].y == m) li = 2 * i + 1;
      if (D[i].x == m) li = 2 * i;
    }
    // wave max via DPP; index recovery via ballot (lane order == index order,
    // so first set lane == smallest point index among wave maxima).
    float wm = wave_max_to_lane63(m);
    float wavemax = __int_as_float(
        __builtin_amdgcn_readlane(__float_as_int(wm), 63));
    unsigned long long bal = __ballot(m == wavemax);
    int firstlane = (int)__builtin_ctzll(bal);
    int widx = __builtin_amdgcn_readlane(p0 + li, firstlane);
    // packed key: high = f32 bits (monotone for +finite), low = 8191-idx so
    // larger key == (larger dist, then smaller index).
    unsigned long long key =
        ((unsigned long long)__float_as_uint(wavemax) << 32) |
        (unsigned)(8191 - widx);
    if (lane == 0) s_red[r & 1][w] = key;
    __syncthreads();
    // all lanes read key (lane&7); 3-step DPP row_shr u64-max -> lane 7.
    {
      unsigned long long kk = s_red[r & 1][lane & 7];
      int hi = (int)(kk >> 32), lo = (int)(kk & 0xffffffffull);
      DPP_U64MAX_STEP(0x111);  // row_shr:1
      DPP_U64MAX_STEP(0x112);  // row_shr:2
      DPP_U64MAX_STEP(0x114);  // row_shr:4 -> lane 7 holds max of lanes 0-7
      int klo = __builtin_amdgcn_readlane(lo, 7);
      const int bi = 8191 - (klo & 0x3fff);
      lx = s_xyz[bi * 3 + 0];  // LDS broadcast read (all lanes same addr)
      ly = s_xyz[bi * 3 + 1];
      lz = s_xyz[bi * 3 + 2];
    }
    if (t == 0) {  // LDS-only winner record; no global store in the loop
      s_ctr[r * 3 + 0] = lx; s_ctr[r * 3 + 1] = ly; s_ctr[r * 3 + 2] = lz;
    }
  }
  __syncthreads();
  // Coalesced writeout: 3072 floats = 768 float4.
  float* o = new_xyz + (size_t)b * S * 3;
  for (int i = t; i < (S * 3) / 4; i += FPS_T) {
    ((float4*)o)[i] = ((const float4*)s_ctr)[i];
  }
}

// ---------------------------------------------------------------------------
// K2: ball query. One wave per center; ordered first-32-within-radius via
// ballot + popc rank; early exit once 32 found; pad with index 0.
// ---------------------------------------------------------------------------
__global__ __launch_bounds__(256) void k_ball(const float* __restrict__ xyz,
                                              const float* __restrict__ new_xyz,
                                              int* __restrict__ ball_idx) {
#pragma clang fp contract(off)
  constexpr float R2 = (float)(0.2 * 0.2);
  const int t = threadIdx.x;
  const int wv = (blockIdx.x << 2) + (t >> 6);
  const int lane = t & 63;
  const int b = wv >> 10;
  const float* base = xyz + (size_t)b * N * 3;
  const float* c = new_xyz + (size_t)wv * 3;
  float cx = c[0], cy = c[1], cz = c[2];
  int* out = ball_idx + (size_t)wv * NS;
  int cnt = 0;
  for (int c0 = 0; c0 < N && cnt < NS; c0 += 64) {
    int p = c0 + lane;
    float x = base[p * 3], y = base[p * 3 + 1], z = base[p * 3 + 2];
    float dx = x - cx, dy = y - cy, dz = z - cz;
    float d = (dx * dx + dy * dy) + dz * dz;
    bool v = d < R2;
    unsigned long long mk = __ballot(v);
    int rank = cnt + __popcll(mk & ((1ull << lane) - 1ull));
    if (v && rank < NS) out[rank] = p;
    cnt += (int)__popcll(mk);
  }
  if (cnt < NS)
    for (int j = cnt + lane; j < NS; j += 64) out[j] = 0;
}

// ---------------------------------------------------------------------------
// K3: gather + 3-layer MLP (BN folded into weights) + max over nsample.
// One wave per center; lane = output channel; weights in registers;
// activations in per-wave LDS buffer read via broadcast. Layer 3 computes
// both channel halves per n-pass (one LDS read feeds two register rows).
// ---------------------------------------------------------------------------
__global__ void __attribute__((amdgpu_flat_work_group_size(256, 256),
                               amdgpu_waves_per_eu(2, 2)))
k_mlp(const float* __restrict__ xyz, const int* __restrict__ ball_idx,
      const float* __restrict__ w1, const float* __restrict__ b1,
      const float* __restrict__ g1, const float* __restrict__ be1,
      const float* __restrict__ m1, const float* __restrict__ v1,
      const float* __restrict__ w2, const float* __restrict__ b2,
      const float* __restrict__ g2, const float* __restrict__ be2,
      const float* __restrict__ m2, const float* __restrict__ v2,
      const float* __restrict__ w3, const float* __restrict__ b3,
      const float* __restrict__ g3, const float* __restrict__ be3,
      const float* __restrict__ m3, const float* __restrict__ v3,
      float* __restrict__ out_feat) {
  const int t = threadIdx.x;
  const int w = t >> 6, lane = t & 63;
  const int wv = (blockIdx.x << 2) + w;
  const int b = wv >> 10, s = wv & (S - 1);
  __shared__ float sh[4][NS * 64];
  __shared__ float sc[4][NS * 4];
  float* h = sh[w];
  float* cs = sc[w];
  const int* gi = ball_idx + (size_t)wv * NS;
  const float* base = xyz + (size_t)b * N * 3;
  if (lane < NS) {
    int p = gi[lane];
    cs[lane * 4 + 0] = base[p * 3 + 0];
    cs[lane * 4 + 1] = base[p * 3 + 1];
    cs[lane * 4 + 2] = base[p * 3 + 2];
  }
  __syncthreads();
  // ---- layer 1: 3 -> 64 ----
  {
    float sv = g1[lane] / sqrtf(v1[lane] + BN_EPS);
    float bb = (b1[lane] - m1[lane]) * sv + be1[lane];
    float wx = w1[lane * 3 + 0] * sv, wy = w1[lane * 3 + 1] * sv,
          wz = w1[lane * 3 + 2] * sv;
    for (int n = 0; n < NS; ++n) {
      float a = fmaf(wx, cs[n * 4 + 0],
                     fmaf(wy, cs[n * 4 + 1], fmaf(wz, cs[n * 4 + 2], bb)));
      h[n * 64 + lane] = fmaxf(a, 0.f);
    }
  }
  __syncthreads();
  // ---- layer 2: 64 -> 64 (in-place row overwrite, wave-lockstep safe) ----
  {
    float sv = g2[lane] / sqrtf(v2[lane] + BN_EPS);
    float bb = (b2[lane] - m2[lane]) * sv + be2[lane];
    float W[64];
#pragma unroll
    for (int k = 0; k < 64; k += 4) {
      float4 q = *(const float4*)(w2 + lane * 64 + k);
      W[k + 0] = q.x * sv; W[k + 1] = q.y * sv;
      W[k + 2] = q.z * sv; W[k + 3] = q.w * sv;
    }
    for (int n = 0; n < NS; ++n) {
      float acc = bb;
#pragma unroll
      for (int k = 0; k < 64; k += 4) {
        float4 q = *(const float4*)(h + n * 64 + k);
        acc = fmaf(W[k + 0], q.x, acc);
        acc = fmaf(W[k + 1], q.y, acc);
        acc = fmaf(W[k + 2], q.z, acc);
        acc = fmaf(W[k + 3], q.w, acc);
      }
      h[n * 64 + lane] = fmaxf(acc, 0.f);
    }
  }
  __syncthreads();
  // ---- layer 3: 64 -> 128, both channel halves per n-pass, fused max ----
  float mxa = 0.f, mxb = 0.f;  // max(relu(x)) == max(0, max(x))
  {
    float sva = g3[lane] / sqrtf(v3[lane] + BN_EPS);
    float bba = (b3[lane] - m3[lane]) * sva + be3[lane];
    float svb = g3[lane + 64] / sqrtf(v3[lane + 64] + BN_EPS);
    float bbb = (b3[lane + 64] - m3[lane + 64]) * svb + be3[lane + 64];
    float Wa[64], Wb[64];
#pragma unroll
    for (int k = 0; k < 64; k += 4) {
      float4 qa = *(const float4*)(w3 + lane * 64 + k);
      Wa[k + 0] = qa.x * sva; Wa[k + 1] = qa.y * sva;
      Wa[k + 2] = qa.z * sva; Wa[k + 3] = qa.w * sva;
      float4 qb = *(const float4*)(w3 + (lane + 64) * 64 + k);
      Wb[k + 0] = qb.x * svb; Wb[k + 1] = qb.y * svb;
      Wb[k + 2] = qb.z * svb; Wb[k + 3] = qb.w * svb;
    }
    for (int n = 0; n < NS; ++n) {
      float acca = bba, accb = bbb;
#pragma unroll
      for (int k = 0; k < 64; k += 4) {
        float4 q = *(const float4*)(h + n * 64 + k);  // one read, two rows
        acca = fmaf(Wa[k + 0], q.x, acca);
        acca = fmaf(Wa[k + 1], q.y, acca);
        acca = fmaf(Wa[k + 2], q.z, acca);
        acca = fmaf(Wa[k + 3], q.w, acca);
        accb = fmaf(Wb[k + 0], q.x, accb);
        accb = fmaf(Wb[k + 1], q.y, accb);
        accb = fmaf(Wb[k + 2], q.z, accb);
        accb = fmaf(Wb[k + 3], q.w, accb);
      }
      mxa = fmaxf(mxa, acca);
      mxb = fmaxf(mxb, accb);
    }
  }
  out_feat[((size_t)b * 128 + lane) * S + s] = mxa;
  out_feat[((size_t)b * 128 + 64 + lane) * S + s] = mxb;
}

// ---------------------------------------------------------------------------
extern "C" void kernel_launch(void* const* d_in, const int* in_sizes, int n_in,
                              void* d_out, int out_size, void* d_ws,
                              size_t ws_size, hipStream_t stream) {
  const float* xyz = (const float*)d_in[0];
  const float* w1 = (const float*)d_in[1];
  const float* b1 = (const float*)d_in[2];
  const float* g1 = (const float*)d_in[3];
  const float* be1 = (const float*)d_in[4];
  const float* m1 = (const float*)d_in[5];
  const float* v1 = (const float*)d_in[6];
  const float* w2 = (const float*)d_in[7];
  const float* b2 = (const float*)d_in[8];
  const float* g2 = (const float*)d_in[9];
  const float* be2 = (const float*)d_in[10];
  const float* m2 = (const float*)d_in[11];
  const float* v2 = (const float*)d_in[12];
  const float* w3 = (const float*)d_in[13];
  const float* b3 = (const float*)d_in[14];
  const float* g3 = (const float*)d_in[15];
  const float* be3 = (const float*)d_in[16];
  const float* m3 = (const float*)d_in[17];
  const float* v3 = (const float*)d_in[18];

  float* out = (float*)d_out;
  float* new_xyz = out;                        // (B, S, 3)
  float* out_feat = out + (size_t)B * S * 3;   // (B, 128, S)
  int* ball = (int*)d_ws;                      // (B, S, NS) int32, 1 MiB

  k_fps<<<B, FPS_T, N * 3 * sizeof(float), stream>>>(xyz, new_xyz);
  k_ball<<<(B * S) / 4, 256, 0, stream>>>(xyz, new_xyz, ball);
  k_mlp<<<(B * S) / 4, 256, 0, stream>>>(xyz, ball, w1, b1, g1, be1, m1, v1,
                                         w2, b2, g2, be2, m2, v2, w3, b3, g3,
                                         be3, m3, v3, out_feat);
}

// Round 7
// 1065.797 us; speedup vs baseline: 1.0777x; 1.0777x over previous
//
#include <hip/hip_runtime.h>

#define B 8
#define N 8192
#define S 1024
#define NS 32
constexpr float BN_EPS = 1e-5f;

typedef float v2f __attribute__((ext_vector_type(2)));

// DPP-based full-wave (64-lane) f32 max; result valid in lane 63.
__device__ __forceinline__ float wave_max_to_lane63(float x) {
  int v = __float_as_int(x);
#define DPP_MAX(ctrl)                                                     \
  v = __float_as_int(fmaxf(__int_as_float(v),                             \
      __int_as_float(__builtin_amdgcn_update_dpp(v, v, (ctrl), 0xf, 0xf, \
                                                 false))))
  DPP_MAX(0x111);  // row_shr:1
  DPP_MAX(0x112);  // row_shr:2
  DPP_MAX(0x114);  // row_shr:4
  DPP_MAX(0x118);  // row_shr:8  -> lane15/31/47/63 hold row maxima
  DPP_MAX(0x142);  // row_bcast:15 -> lane31 = rows0-1, lane63 = rows2-3
  DPP_MAX(0x143);  // row_bcast:31 -> lane63 = all 64
#undef DPP_MAX
  return __int_as_float(v);
}

// ---------------------------------------------------------------------------
// K1: furthest point sampling. One block per batch; 512 threads, 16 pts/thread
// register-resident (waves_per_eu(2,2), 88 VGPR, no spill - verified R4).
// R7 changes (instruction-count + serial-tail cuts):
//  - D-update min is packed (v_pk_min_f32 via __builtin_elementwise_min);
//    R6 used 16 scalar fminf.
//  - Local argmax index via max-tree + walk-down (~15 instr) instead of the
//    32-instr equality scan; prefer-left on ties == first occurrence.
//  - Cross-wave reduce reverted to R4's PARALLEL form (8 ds_read_b64 +
//    unrolled u64-max tree). R6's DPP-u64 chain was a serial-latency tail
//    and measured SLOWER (922 vs 873 us).
//  - Winner coords: ONE ds_read_b128 from a float4-strided LDS mirror
//    (128 KB) instead of 3 dependent ds_read_b32.
// Exact contract-off fp32 distance math -> argmax selections match the NumPy
// reference bit-for-bit; ties -> smallest index via (8191-idx) key low word.
// ---------------------------------------------------------------------------
#define FPS_T 512

__global__ void __attribute__((amdgpu_flat_work_group_size(FPS_T, FPS_T),
                               amdgpu_waves_per_eu(2, 2)))
k_fps(const float* __restrict__ xyz, float* __restrict__ new_xyz) {
#pragma clang fp contract(off)
  extern __shared__ float4 s_xyz4[];  // N float4 = 128 KB (x,y,z,pad)
  __shared__ alignas(16) float s_ctr[S * 3];  // chosen centers, 12 KB
  __shared__ unsigned long long s_red[2][8];
  const int b = blockIdx.x;
  const int t = threadIdx.x;
  const int lane = t & 63;
  const int w = t >> 6;
  const float* base = xyz + (size_t)b * N * 3;
  v2f X[8], Y[8], Z[8], D[8];
  const int p0 = t * 16;
  {
    // 16 pts * 3 floats = 12 float4 global loads, 16B-aligned (t*192 bytes);
    // re-packed into a float4-strided LDS mirror for 1-instr coord broadcast.
    const float4* src = (const float4*)(base + (size_t)p0 * 3);
    float buf[48];
#pragma unroll
    for (int i = 0; i < 12; ++i) {
      float4 v = src[i];
      buf[4 * i + 0] = v.x; buf[4 * i + 1] = v.y;
      buf[4 * i + 2] = v.z; buf[4 * i + 3] = v.w;
    }
#pragma unroll
    for (int k = 0; k < 16; ++k) {
      s_xyz4[p0 + k] =
          make_float4(buf[3 * k], buf[3 * k + 1], buf[3 * k + 2], 0.f);
    }
#pragma unroll
    for (int i = 0; i < 8; ++i) {
      X[i] = (v2f){buf[6 * i + 0], buf[6 * i + 3]};
      Y[i] = (v2f){buf[6 * i + 1], buf[6 * i + 4]};
      Z[i] = (v2f){buf[6 * i + 2], buf[6 * i + 5]};
      D[i] = (v2f){3.4e38f, 3.4e38f};  // ref init +inf; min(inf,d)=d, d<=3
    }
  }
  float lx = base[0], ly = base[1], lz = base[2];  // start index 0
  if (t == 0) {
    s_ctr[0] = lx; s_ctr[1] = ly; s_ctr[2] = lz;
  }
  for (int r = 1; r < S; ++r) {
    v2f lx2 = lx, ly2 = ly, lz2 = lz;
    // exact: d = ((dx*dx)+(dy*dy))+(dz*dz), contraction off; pk ops round
    // identically to scalar per lane-half.
#pragma unroll
    for (int i = 0; i < 8; ++i) {
      v2f dx = X[i] - lx2, dy = Y[i] - ly2, dz = Z[i] - lz2;
      v2f d = (dx * dx + dy * dy) + dz * dz;
      D[i] = __builtin_elementwise_min(D[i], d);  // v_pk_min_f32
    }
    // local max tree over the 16 halves (leaf j = D[j>>1].{x:even,y:odd})
    float n1[8], n2[4], n3[2];
#pragma unroll
    for (int i = 0; i < 8; ++i) n1[i] = fmaxf(D[i].x, D[i].y);
#pragma unroll
    for (int i = 0; i < 4; ++i) n2[i] = fmaxf(n1[2 * i], n1[2 * i + 1]);
    n3[0] = fmaxf(n2[0], n2[1]);
    n3[1] = fmaxf(n2[2], n2[3]);
    float m = fmaxf(n3[0], n3[1]);
    // walk-down, prefer-left on equality == first (smallest) index
    int c3 = (n3[0] < m) ? 1 : 0;
    float n2s = c3 ? n2[2] : n2[0];
    int c2 = (n2s < m) ? 1 : 0;
    float n1a = c3 ? n1[4] : n1[0];
    float n1b = c3 ? n1[6] : n1[2];
    float n1s = c2 ? n1b : n1a;
    int c1 = (n1s < m) ? 1 : 0;
    float dx0 = c3 ? D[4].x : D[0].x;
    float dx1 = c3 ? D[5].x : D[1].x;
    float dx2 = c3 ? D[6].x : D[2].x;
    float dx3 = c3 ? D[7].x : D[3].x;
    float dxa = c2 ? dx2 : dx0;
    float dxb = c2 ? dx3 : dx1;
    float dxs = c1 ? dxb : dxa;
    int c0 = (dxs < m) ? 1 : 0;
    int li = 8 * c3 + 4 * c2 + 2 * c1 + c0;
    // wave max via DPP; index recovery via ballot (lane order == index order,
    // so first set lane == smallest point index among wave maxima).
    float wm = wave_max_to_lane63(m);
    float wavemax = __int_as_float(
        __builtin_amdgcn_readlane(__float_as_int(wm), 63));
    unsigned long long bal = __ballot(m == wavemax);
    int firstlane = (int)__builtin_ctzll(bal);
    int widx = __builtin_amdgcn_readlane(p0 + li, firstlane);
    // packed key: high = f32 bits (monotone for +finite), low = 8191-idx so
    // larger key == (larger dist, then smaller index). Keys unique per wave.
    unsigned long long key =
        ((unsigned long long)__float_as_uint(wavemax) << 32) |
        (unsigned)(8191 - widx);
    if (lane == 0) s_red[r & 1][w] = key;
    __syncthreads();
    // parallel cross-wave reduce: 8 broadcast LDS reads + u64 max tree
    {
      const unsigned long long* sr = s_red[r & 1];
      unsigned long long k0 = sr[0], k1 = sr[1], k2 = sr[2], k3 = sr[3];
      unsigned long long k4 = sr[4], k5 = sr[5], k6 = sr[6], k7 = sr[7];
      unsigned long long a = k0 > k1 ? k0 : k1;
      unsigned long long c = k2 > k3 ? k2 : k3;
      unsigned long long e = k4 > k5 ? k4 : k5;
      unsigned long long g = k6 > k7 ? k6 : k7;
      unsigned long long ac = a > c ? a : c;
      unsigned long long eg = e > g ? e : g;
      unsigned long long kmax = ac > eg ? ac : eg;
      const int bi = 8191 - (int)(unsigned)(kmax & 0xffffffffull);
      float4 cc = s_xyz4[bi];  // ONE ds_read_b128, broadcast
      lx = cc.x; ly = cc.y; lz = cc.z;
    }
    if (t == 0) {  // LDS-only winner record; no global store in the loop
      s_ctr[r * 3 + 0] = lx; s_ctr[r * 3 + 1] = ly; s_ctr[r * 3 + 2] = lz;
    }
  }
  __syncthreads();
  // Coalesced writeout: 3072 floats = 768 float4.
  float* o = new_xyz + (size_t)b * S * 3;
  for (int i = t; i < (S * 3) / 4; i += FPS_T) {
    ((float4*)o)[i] = ((const float4*)s_ctr)[i];
  }
}

// ---------------------------------------------------------------------------
// K2: ball query. One wave per center; ordered first-32-within-radius via
// ballot + popc rank; early exit once 32 found; pad with index 0.
// ---------------------------------------------------------------------------
__global__ __launch_bounds__(256) void k_ball(const float* __restrict__ xyz,
                                              const float* __restrict__ new_xyz,
                                              int* __restrict__ ball_idx) {
#pragma clang fp contract(off)
  constexpr float R2 = (float)(0.2 * 0.2);
  const int t = threadIdx.x;
  const int wv = (blockIdx.x << 2) + (t >> 6);
  const int lane = t & 63;
  const int b = wv >> 10;
  const float* base = xyz + (size_t)b * N * 3;
  const float* c = new_xyz + (size_t)wv * 3;
  float cx = c[0], cy = c[1], cz = c[2];
  int* out = ball_idx + (size_t)wv * NS;
  int cnt = 0;
  for (int c0 = 0; c0 < N && cnt < NS; c0 += 64) {
    int p = c0 + lane;
    float x = base[p * 3], y = base[p * 3 + 1], z = base[p * 3 + 2];
    float dx = x - cx, dy = y - cy, dz = z - cz;
    float d = (dx * dx + dy * dy) + dz * dz;
    bool v = d < R2;
    unsigned long long mk = __ballot(v);
    int rank = cnt + __popcll(mk & ((1ull << lane) - 1ull));
    if (v && rank < NS) out[rank] = p;
    cnt += (int)__popcll(mk);
  }
  if (cnt < NS)
    for (int j = cnt + lane; j < NS; j += 64) out[j] = 0;
}

// ---------------------------------------------------------------------------
// K3: gather + 3-layer MLP (BN folded into weights) + max over nsample.
// One wave per center; lane = output channel; weights in registers;
// activations in per-wave LDS buffer read via broadcast. Layer 3 computes
// both channel halves per n-pass (one LDS read feeds two register rows).
// ---------------------------------------------------------------------------
__global__ void __attribute__((amdgpu_flat_work_group_size(256, 256),
                               amdgpu_waves_per_eu(2, 2)))
k_mlp(const float* __restrict__ xyz, const int* __restrict__ ball_idx,
      const float* __restrict__ w1, const float* __restrict__ b1,
      const float* __restrict__ g1, const float* __restrict__ be1,
      const float* __restrict__ m1, const float* __restrict__ v1,
      const float* __restrict__ w2, const float* __restrict__ b2,
      const float* __restrict__ g2, const float* __restrict__ be2,
      const float* __restrict__ m2, const float* __restrict__ v2,
      const float* __restrict__ w3, const float* __restrict__ b3,
      const float* __restrict__ g3, const float* __restrict__ be3,
      const float* __restrict__ m3, const float* __restrict__ v3,
      float* __restrict__ out_feat) {
  const int t = threadIdx.x;
  const int w = t >> 6, lane = t & 63;
  const int wv = (blockIdx.x << 2) + w;
  const int b = wv >> 10, s = wv & (S - 1);
  __shared__ float sh[4][NS * 64];
  __shared__ float sc[4][NS * 4];
  float* h = sh[w];
  float* cs = sc[w];
  const int* gi = ball_idx + (size_t)wv * NS;
  const float* base = xyz + (size_t)b * N * 3;
  if (lane < NS) {
    int p = gi[lane];
    cs[lane * 4 + 0] = base[p * 3 + 0];
    cs[lane * 4 + 1] = base[p * 3 + 1];
    cs[lane * 4 + 2] = base[p * 3 + 2];
  }
  __syncthreads();
  // ---- layer 1: 3 -> 64 ----
  {
    float sv = g1[lane] / sqrtf(v1[lane] + BN_EPS);
    float bb = (b1[lane] - m1[lane]) * sv + be1[lane];
    float wx = w1[lane * 3 + 0] * sv, wy = w1[lane * 3 + 1] * sv,
          wz = w1[lane * 3 + 2] * sv;
    for (int n = 0; n < NS; ++n) {
      float a = fmaf(wx, cs[n * 4 + 0],
                     fmaf(wy, cs[n * 4 + 1], fmaf(wz, cs[n * 4 + 2], bb)));
      h[n * 64 + lane] = fmaxf(a, 0.f);
    }
  }
  __syncthreads();
  // ---- layer 2: 64 -> 64 (in-place row overwrite, wave-lockstep safe) ----
  {
    float sv = g2[lane] / sqrtf(v2[lane] + BN_EPS);
    float bb = (b2[lane] - m2[lane]) * sv + be2[lane];
    float W[64];
#pragma unroll
    for (int k = 0; k < 64; k += 4) {
      float4 q = *(const float4*)(w2 + lane * 64 + k);
      W[k + 0] = q.x * sv; W[k + 1] = q.y * sv;
      W[k + 2] = q.z * sv; W[k + 3] = q.w * sv;
    }
    for (int n = 0; n < NS; ++n) {
      float acc = bb;
#pragma unroll
      for (int k = 0; k < 64; k += 4) {
        float4 q = *(const float4*)(h + n * 64 + k);
        acc = fmaf(W[k + 0], q.x, acc);
        acc = fmaf(W[k + 1], q.y, acc);
        acc = fmaf(W[k + 2], q.z, acc);
        acc = fmaf(W[k + 3], q.w, acc);
      }
      h[n * 64 + lane] = fmaxf(acc, 0.f);
    }
  }
  __syncthreads();
  // ---- layer 3: 64 -> 128, both channel halves per n-pass, fused max ----
  float mxa = 0.f, mxb = 0.f;  // max(relu(x)) == max(0, max(x))
  {
    float sva = g3[lane] / sqrtf(v3[lane] + BN_EPS);
    float bba = (b3[lane] - m3[lane]) * sva + be3[lane];
    float svb = g3[lane + 64] / sqrtf(v3[lane + 64] + BN_EPS);
    float bbb = (b3[lane + 64] - m3[lane + 64]) * svb + be3[lane + 64];
    float Wa[64], Wb[64];
#pragma unroll
    for (int k = 0; k < 64; k += 4) {
      float4 qa = *(const float4*)(w3 + lane * 64 + k);
      Wa[k + 0] = qa.x * sva; Wa[k + 1] = qa.y * sva;
      Wa[k + 2] = qa.z * sva; Wa[k + 3] = qa.w * sva;
      float4 qb = *(const float4*)(w3 + (lane + 64) * 64 + k);
      Wb[k + 0] = qb.x * svb; Wb[k + 1] = qb.y * svb;
      Wb[k + 2] = qb.z * svb; Wb[k + 3] = qb.w * svb;
    }
    for (int n = 0; n < NS; ++n) {
      float acca = bba, accb = bbb;
#pragma unroll
      for (int k = 0; k < 64; k += 4) {
        float4 q = *(const float4*)(h + n * 64 + k);  // one read, two rows
        acca = fmaf(Wa[k + 0], q.x, acca);
        acca = fmaf(Wa[k + 1], q.y, acca);
        acca = fmaf(Wa[k + 2], q.z, acca);
        acca = fmaf(Wa[k + 3], q.w, acca);
        accb = fmaf(Wb[k + 0], q.x, accb);
        accb = fmaf(Wb[k + 1], q.y, accb);
        accb = fmaf(Wb[k + 2], q.z, accb);
        accb = fmaf(Wb[k + 3], q.w, accb);
      }
      mxa = fmaxf(mxa, acca);
      mxb = fmaxf(mxb, accb);
    }
  }
  out_feat[((size_t)b * 128 + lane) * S + s] = mxa;
  out_feat[((size_t)b * 128 + 64 + lane) * S + s] = mxb;
}

// ---------------------------------------------------------------------------
extern "C" void kernel_launch(void* const* d_in, const int* in_sizes, int n_in,
                              void* d_out, int out_size, void* d_ws,
                              size_t ws_size, hipStream_t stream) {
  const float* xyz = (const float*)d_in[0];
  const float* w1 = (const float*)d_in[1];
  const float* b1 = (const float*)d_in[2];
  const float* g1 = (const float*)d_in[3];
  const float* be1 = (const float*)d_in[4];
  const float* m1 = (const float*)d_in[5];
  const float* v1 = (const float*)d_in[6];
  const float* w2 = (const float*)d_in[7];
  const float* b2 = (const float*)d_in[8];
  const float* g2 = (const float*)d_in[9];
  const float* be2 = (const float*)d_in[10];
  const float* m2 = (const float*)d_in[11];
  const float* v2 = (const float*)d_in[12];
  const float* w3 = (const float*)d_in[13];
  const float* b3 = (const float*)d_in[14];
  const float* g3 = (const float*)d_in[15];
  const float* be3 = (const float*)d_in[16];
  const float* m3 = (const float*)d_in[17];
  const float* v3 = (const float*)d_in[18];

  float* out = (float*)d_out;
  float* new_xyz = out;                        // (B, S, 3)
  float* out_feat = out + (size_t)B * S * 3;   // (B, 128, S)
  int* ball = (int*)d_ws;                      // (B, S, NS) int32, 1 MiB

  k_fps<<<B, FPS_T, N * sizeof(float4), stream>>>(xyz, new_xyz);
  k_ball<<<(B * S) / 4, 256, 0, stream>>>(xyz, new_xyz, ball);
  k_mlp<<<(B * S) / 4, 256, 0, stream>>>(xyz, ball, w1, b1, g1, be1, m1, v1,
                                         w2, b2, g2, be2, m2, v2, w3, b3, g3,
                                         be3, m3, v3, out_feat);
}

// Round 8
// 1048.900 us; speedup vs baseline: 1.0950x; 1.0161x over previous
//
#include <hip/hip_runtime.h>

#define B 8
#define N 8192
#define S 1024
#define NS 32
#define THREADS 512
#define NCONS_BLK 248
#define NCONS_WAVE (NCONS_BLK * 8)
constexpr float BN_EPS = 1e-5f;

typedef float v2f __attribute__((ext_vector_type(2)));

struct KParams {
  const float* xyz;
  const float *w1, *b1, *g1, *be1, *m1, *v1;
  const float *w2, *b2, *g2, *be2, *m2, *v2;
  const float *w3, *b3, *g3, *be3, *m3, *v3;
  float* new_xyz;   // d_out (B,S,3)
  float* out_feat;  // d_out + B*S*3 (B,128,S)
  float* ctrs;      // d_ws+2048: (B, S*3) published centers
  unsigned* prog;   // d_ws: per-batch progress counter, 64-int stride
};

// DPP-based full-wave (64-lane) f32 max; result valid in lane 63.
__device__ __forceinline__ float wave_max_to_lane63(float x) {
  int v = __float_as_int(x);
#define DPP_MAX(ctrl)                                                     \
  v = __float_as_int(fmaxf(__int_as_float(v),                             \
      __int_as_float(__builtin_amdgcn_update_dpp(v, v, (ctrl), 0xf, 0xf, \
                                                 false))))
  DPP_MAX(0x111);
  DPP_MAX(0x112);
  DPP_MAX(0x114);
  DPP_MAX(0x118);
  DPP_MAX(0x142);
  DPP_MAX(0x143);
#undef DPP_MAX
  return __int_as_float(v);
}

// ---------------------------------------------------------------------------
// Producer: R7 fps, unchanged logic, plus an every-8-rounds publish of the
// chunk of centers (agent-scope atomic stores; release-store of prog).
// Exact contract-off fp32 distance math -> argmax matches NumPy bit-for-bit.
// ---------------------------------------------------------------------------
__device__ __forceinline__ void producer(const KParams& P, char* smem, int b,
                                         int t, int lane, int w) {
#pragma clang fp contract(off)
  float4* s_xyz4 = (float4*)smem;                       // 128 KB
  float* s_ctr = (float*)(smem + 131072);               // 12 KB
  unsigned long long(*s_red)[8] =
      (unsigned long long(*)[8])(smem + 131072 + 12288);  // 128 B
  const float* base = P.xyz + (size_t)b * N * 3;
  v2f X[8], Y[8], Z[8], D[8];
  const int p0 = t * 16;
  {
    const float4* src = (const float4*)(base + (size_t)p0 * 3);
    float buf[48];
#pragma unroll
    for (int i = 0; i < 12; ++i) {
      float4 v = src[i];
      buf[4 * i + 0] = v.x; buf[4 * i + 1] = v.y;
      buf[4 * i + 2] = v.z; buf[4 * i + 3] = v.w;
    }
#pragma unroll
    for (int k = 0; k < 16; ++k)
      s_xyz4[p0 + k] =
          make_float4(buf[3 * k], buf[3 * k + 1], buf[3 * k + 2], 0.f);
#pragma unroll
    for (int i = 0; i < 8; ++i) {
      X[i] = (v2f){buf[6 * i + 0], buf[6 * i + 3]};
      Y[i] = (v2f){buf[6 * i + 1], buf[6 * i + 4]};
      Z[i] = (v2f){buf[6 * i + 2], buf[6 * i + 5]};
      D[i] = (v2f){3.4e38f, 3.4e38f};
    }
  }
  float lx = base[0], ly = base[1], lz = base[2];  // start index 0
  if (t == 0) { s_ctr[0] = lx; s_ctr[1] = ly; s_ctr[2] = lz; }
  for (int r = 1; r < S; ++r) {
    v2f lx2 = lx, ly2 = ly, lz2 = lz;
#pragma unroll
    for (int i = 0; i < 8; ++i) {
      v2f dx = X[i] - lx2, dy = Y[i] - ly2, dz = Z[i] - lz2;
      v2f d = (dx * dx + dy * dy) + dz * dz;
      D[i] = __builtin_elementwise_min(D[i], d);
    }
    float n1[8], n2[4], n3[2];
#pragma unroll
    for (int i = 0; i < 8; ++i) n1[i] = fmaxf(D[i].x, D[i].y);
#pragma unroll
    for (int i = 0; i < 4; ++i) n2[i] = fmaxf(n1[2 * i], n1[2 * i + 1]);
    n3[0] = fmaxf(n2[0], n2[1]);
    n3[1] = fmaxf(n2[2], n2[3]);
    float m = fmaxf(n3[0], n3[1]);
    int c3 = (n3[0] < m) ? 1 : 0;
    float n2s = c3 ? n2[2] : n2[0];
    int c2 = (n2s < m) ? 1 : 0;
    float n1a = c3 ? n1[4] : n1[0];
    float n1b = c3 ? n1[6] : n1[2];
    float n1s = c2 ? n1b : n1a;
    int c1 = (n1s < m) ? 1 : 0;
    float dx0 = c3 ? D[4].x : D[0].x;
    float dx1 = c3 ? D[5].x : D[1].x;
    float dx2 = c3 ? D[6].x : D[2].x;
    float dx3 = c3 ? D[7].x : D[3].x;
    float dxa = c2 ? dx2 : dx0;
    float dxb = c2 ? dx3 : dx1;
    float dxs = c1 ? dxb : dxa;
    int c0 = (dxs < m) ? 1 : 0;
    int li = 8 * c3 + 4 * c2 + 2 * c1 + c0;
    float wm = wave_max_to_lane63(m);
    float wavemax =
        __int_as_float(__builtin_amdgcn_readlane(__float_as_int(wm), 63));
    unsigned long long bal = __ballot(m == wavemax);
    int firstlane = (int)__builtin_ctzll(bal);
    int widx = __builtin_amdgcn_readlane(p0 + li, firstlane);
    unsigned long long key =
        ((unsigned long long)__float_as_uint(wavemax) << 32) |
        (unsigned)(8191 - widx);
    if (lane == 0) s_red[r & 1][w] = key;
    __syncthreads();
    {
      const unsigned long long* sr = s_red[r & 1];
      unsigned long long k0 = sr[0], k1 = sr[1], k2 = sr[2], k3 = sr[3];
      unsigned long long k4 = sr[4], k5 = sr[5], k6 = sr[6], k7 = sr[7];
      unsigned long long a = k0 > k1 ? k0 : k1;
      unsigned long long c = k2 > k3 ? k2 : k3;
      unsigned long long e = k4 > k5 ? k4 : k5;
      unsigned long long g = k6 > k7 ? k6 : k7;
      unsigned long long ac = a > c ? a : c;
      unsigned long long eg = e > g ? e : g;
      unsigned long long kmax = ac > eg ? ac : eg;
      const int bi = 8191 - (int)(unsigned)(kmax & 0xffffffffull);
      float4 cc = s_xyz4[bi];
      lx = cc.x; ly = cc.y; lz = cc.z;
    }
    if (t == 0) {
      s_ctr[r * 3 + 0] = lx; s_ctr[r * 3 + 1] = ly; s_ctr[r * 3 + 2] = lz;
    }
    // publish chunk of 8 centers: lanes 0-23 store 24 floats (agent-scope,
    // bypasses local L2 to the device coherence point), lane 0 release-stores
    // the progress counter (waits vmcnt -> coord stores complete first).
    if (w == 0 && (r & 7) == 7) {
      int cbase = (r - 7) * 3;  // multiple of 24 -> 16B-aligned chunk
      if (lane < 24) {
        float v = s_ctr[cbase + lane];
        __hip_atomic_store(P.ctrs + (size_t)b * (S * 3) + cbase + lane, v,
                           __ATOMIC_RELAXED, __HIP_MEMORY_SCOPE_AGENT);
      }
      if (lane == 0)
        __hip_atomic_store(&P.prog[b * 64], (unsigned)(r + 1),
                           __ATOMIC_RELEASE, __HIP_MEMORY_SCOPE_AGENT);
    }
  }
  __syncthreads();
  float* o = P.new_xyz + (size_t)b * S * 3;
  for (int i = t; i < (S * 3) / 4; i += THREADS)
    ((float4*)o)[i] = ((const float4*)s_ctr)[i];
}

// ---------------------------------------------------------------------------
// Consumer: one wave per center. Spin until the producer publishes center
// (b, s); ball query fused with coord gather (finder lanes scatter coords
// straight into per-wave LDS); 3-layer BN-folded MLP + max. No block
// barriers: all LDS RAW hazards are same-wave (compiler-ordered lgkmcnt).
// ---------------------------------------------------------------------------
__device__ __forceinline__ void consumer(const KParams& P, char* smem, int cid,
                                         int t, int lane, int w) {
#pragma clang fp contract(off)
  constexpr float R2 = (float)(0.2 * 0.2);
  float* h = (float*)smem + w * (NS * 64);            // 8 KB per wave
  float* cs = (float*)smem + 8 * NS * 64 + w * (NS * 4);
  const unsigned gw = cid * 8 + w;  // global consumer wave id, 0..1983
  // BN-folded weights, loaded once per wave (registers)
  float sv1 = P.g1[lane] / sqrtf(P.v1[lane] + BN_EPS);
  float bb1 = (P.b1[lane] - P.m1[lane]) * sv1 + P.be1[lane];
  float w1x = P.w1[lane * 3 + 0] * sv1, w1y = P.w1[lane * 3 + 1] * sv1,
        w1z = P.w1[lane * 3 + 2] * sv1;
  float sv2 = P.g2[lane] / sqrtf(P.v2[lane] + BN_EPS);
  float bb2 = (P.b2[lane] - P.m2[lane]) * sv2 + P.be2[lane];
  float W2[64];
#pragma unroll
  for (int k = 0; k < 64; k += 4) {
    float4 q = *(const float4*)(P.w2 + lane * 64 + k);
    W2[k + 0] = q.x * sv2; W2[k + 1] = q.y * sv2;
    W2[k + 2] = q.z * sv2; W2[k + 3] = q.w * sv2;
  }
  float sva = P.g3[lane] / sqrtf(P.v3[lane] + BN_EPS);
  float bba = (P.b3[lane] - P.m3[lane]) * sva + P.be3[lane];
  float svb = P.g3[lane + 64] / sqrtf(P.v3[lane + 64] + BN_EPS);
  float bbb = (P.b3[lane + 64] - P.m3[lane + 64]) * svb + P.be3[lane + 64];
  float Wa[64], Wb[64];
#pragma unroll
  for (int k = 0; k < 64; k += 4) {
    float4 qa = *(const float4*)(P.w3 + lane * 64 + k);
    Wa[k + 0] = qa.x * sva; Wa[k + 1] = qa.y * sva;
    Wa[k + 2] = qa.z * sva; Wa[k + 3] = qa.w * sva;
    float4 qb = *(const float4*)(P.w3 + (lane + 64) * 64 + k);
    Wb[k + 0] = qb.x * svb; Wb[k + 1] = qb.y * svb;
    Wb[k + 2] = qb.z * svb; Wb[k + 3] = qb.w * svb;
  }
  for (unsigned c = gw; c < B * S; c += NCONS_WAVE) {
    const int b = c & 7;
    const int s = c >> 3;
    // wait for the producer to publish center (b, s)
    while (__hip_atomic_load(&P.prog[b * 64], __ATOMIC_RELAXED,
                             __HIP_MEMORY_SCOPE_AGENT) <= (unsigned)s)
      __builtin_amdgcn_s_sleep(2);
    (void)__hip_atomic_load(&P.prog[b * 64], __ATOMIC_ACQUIRE,
                            __HIP_MEMORY_SCOPE_AGENT);
    const float* cg = P.ctrs + (size_t)b * (S * 3) + s * 3;
    float cx = __hip_atomic_load(cg + 0, __ATOMIC_RELAXED,
                                 __HIP_MEMORY_SCOPE_AGENT);
    float cy = __hip_atomic_load(cg + 1, __ATOMIC_RELAXED,
                                 __HIP_MEMORY_SCOPE_AGENT);
    float cz = __hip_atomic_load(cg + 2, __ATOMIC_RELAXED,
                                 __HIP_MEMORY_SCOPE_AGENT);
    const float* base = P.xyz + (size_t)b * N * 3;
    // ball query fused with coord gather: finder lane scatters coords to cs
    int cnt = 0;
    for (int c0 = 0; c0 < N && cnt < NS; c0 += 64) {
      int p = c0 + lane;
      float x = base[p * 3], y = base[p * 3 + 1], z = base[p * 3 + 2];
      float dx = x - cx, dy = y - cy, dz = z - cz;
      float d = (dx * dx + dy * dy) + dz * dz;
      bool v = d < R2;  // strict <, exact fp32: matches reference
      unsigned long long mk = __ballot(v);
      int rank = cnt + __popcll(mk & ((1ull << lane) - 1ull));
      if (v && rank < NS) {
        cs[rank * 4 + 0] = x; cs[rank * 4 + 1] = y; cs[rank * 4 + 2] = z;
      }
      cnt += (int)__popcll(mk);
    }
    if (cnt < NS) {  // pad -> point 0 coords (pytorch3d clamp semantics)
      float x0 = base[0], y0 = base[1], z0 = base[2];
      for (int j = cnt + lane; j < NS; j += 64) {
        cs[j * 4 + 0] = x0; cs[j * 4 + 1] = y0; cs[j * 4 + 2] = z0;
      }
    }
    // layer 1: 3 -> 64
    for (int n = 0; n < NS; ++n) {
      float a = fmaf(w1x, cs[n * 4 + 0],
                     fmaf(w1y, cs[n * 4 + 1], fmaf(w1z, cs[n * 4 + 2], bb1)));
      h[n * 64 + lane] = fmaxf(a, 0.f);
    }
    // layer 2: 64 -> 64 (in-place row overwrite, wave-lockstep safe)
    for (int n = 0; n < NS; ++n) {
      float acc = bb2;
#pragma unroll
      for (int k = 0; k < 64; k += 4) {
        float4 q = *(const float4*)(h + n * 64 + k);
        acc = fmaf(W2[k + 0], q.x, acc);
        acc = fmaf(W2[k + 1], q.y, acc);
        acc = fmaf(W2[k + 2], q.z, acc);
        acc = fmaf(W2[k + 3], q.w, acc);
      }
      h[n * 64 + lane] = fmaxf(acc, 0.f);
    }
    // layer 3: 64 -> 128, both halves per pass, fused max over samples
    float mxa = 0.f, mxb = 0.f;
    for (int n = 0; n < NS; ++n) {
      float acca = bba, accb = bbb;
#pragma unroll
      for (int k = 0; k < 64; k += 4) {
        float4 q = *(const float4*)(h + n * 64 + k);
        acca = fmaf(Wa[k + 0], q.x, acca);
        acca = fmaf(Wa[k + 1], q.y, acca);
        acca = fmaf(Wa[k + 2], q.z, acca);
        acca = fmaf(Wa[k + 3], q.w, acca);
        accb = fmaf(Wb[k + 0], q.x, accb);
        accb = fmaf(Wb[k + 1], q.y, accb);
        accb = fmaf(Wb[k + 2], q.z, accb);
        accb = fmaf(Wb[k + 3], q.w, accb);
      }
      mxa = fmaxf(mxa, acca);
      mxb = fmaxf(mxb, accb);
    }
    P.out_feat[((size_t)b * 128 + lane) * S + s] = mxa;
    P.out_feat[((size_t)b * 128 + 64 + lane) * S + s] = mxb;
  }
}

// ---------------------------------------------------------------------------
__global__ void __attribute__((amdgpu_flat_work_group_size(THREADS, THREADS),
                               amdgpu_waves_per_eu(2, 2)))
k_fused(KParams P) {
  extern __shared__ char smem[];
  const int t = threadIdx.x;
  const int lane = t & 63;
  const int w = t >> 6;
  if (blockIdx.x < B)
    producer(P, smem, blockIdx.x, t, lane, w);
  else
    consumer(P, smem, blockIdx.x - B, t, lane, w);
}

// ---------------------------------------------------------------------------
extern "C" void kernel_launch(void* const* d_in, const int* in_sizes, int n_in,
                              void* d_out, int out_size, void* d_ws,
                              size_t ws_size, hipStream_t stream) {
  KParams P;
  P.xyz = (const float*)d_in[0];
  P.w1 = (const float*)d_in[1];  P.b1 = (const float*)d_in[2];
  P.g1 = (const float*)d_in[3];  P.be1 = (const float*)d_in[4];
  P.m1 = (const float*)d_in[5];  P.v1 = (const float*)d_in[6];
  P.w2 = (const float*)d_in[7];  P.b2 = (const float*)d_in[8];
  P.g2 = (const float*)d_in[9];  P.be2 = (const float*)d_in[10];
  P.m2 = (const float*)d_in[11]; P.v2 = (const float*)d_in[12];
  P.w3 = (const float*)d_in[13]; P.b3 = (const float*)d_in[14];
  P.g3 = (const float*)d_in[15]; P.be3 = (const float*)d_in[16];
  P.m3 = (const float*)d_in[17]; P.v3 = (const float*)d_in[18];
  float* out = (float*)d_out;
  P.new_xyz = out;
  P.out_feat = out + (size_t)B * S * 3;
  P.prog = (unsigned*)d_ws;                       // 8 x 64 u32 = 2 KB
  P.ctrs = (float*)((char*)d_ws + 2048);          // 96 KB

  // d_ws is re-poisoned to 0xAA before every timed launch: zero the progress
  // counters (async, graph-capturable) or consumers would see garbage.
  hipMemsetAsync(d_ws, 0, 2048, stream);

  void* args[] = {&P};
  dim3 grid(B + NCONS_BLK), blk(THREADS);
  size_t shmem = 131072 + 12288 + 256;  // producer overlay is the max
  hipError_t e = hipLaunchCooperativeKernel((const void*)k_fused, grid, blk,
                                            args, (unsigned)shmem, stream);
  if (e != hipSuccess) {
    // Fallback: plain launch of the same kernel. 256 blocks x 140KB LDS =
    // 1 block/CU on 256 CUs -> de-facto co-resident.
    k_fused<<<grid, blk, shmem, stream>>>(P);
  }
}

// Round 9
// 950.362 us; speedup vs baseline: 1.2086x; 1.1037x over previous
//
#include <hip/hip_runtime.h>

#define B 8
#define N 8192
#define S 1024
#define NS 32
#define THREADS 256
#define NCONS_BLK 248
#define NCONS_WAVE (NCONS_BLK * 4)
constexpr float BN_EPS = 1e-5f;

typedef float v2f __attribute__((ext_vector_type(2)));

struct KParams {
  const float* xyz;
  const float *w1, *b1, *g1, *be1, *m1, *v1;
  const float *w2, *b2, *g2, *be2, *m2, *v2;
  const float *w3, *b3, *g3, *be3, *m3, *v3;
  float* new_xyz;   // d_out (B,S,3)
  float* out_feat;  // d_out + B*S*3 (B,128,S)
  float* ctrs;      // d_ws+2048: (B, S*3) published centers
  unsigned* prog;   // d_ws: per-batch progress counter, 64-int stride
};

// DPP-based full-wave (64-lane) f32 max; result valid in lane 63.
__device__ __forceinline__ float wave_max_to_lane63(float x) {
  int v = __float_as_int(x);
#define DPP_MAX(ctrl)                                                     \
  v = __float_as_int(fmaxf(__int_as_float(v),                             \
      __int_as_float(__builtin_amdgcn_update_dpp(v, v, (ctrl), 0xf, 0xf, \
                                                 false))))
  DPP_MAX(0x111);
  DPP_MAX(0x112);
  DPP_MAX(0x114);
  DPP_MAX(0x118);
  DPP_MAX(0x142);
  DPP_MAX(0x143);
#undef DPP_MAX
  return __int_as_float(v);
}

// ---------------------------------------------------------------------------
// Producer: FPS with 4 waves (1/SIMD), 32 pts/thread register-resident.
// R9: halves the replicated per-wave reduce work per SIMD (R7 ran 8 waves =
// 2/SIMD; VALUBusy ~75% on active CUs showed issue-bound on that replication).
// Publish uses LAGGED release: release prog for chunk k-1 (stores long since
// drained -> vmcnt wait is instant), THEN issue chunk k's relaxed stores.
// Exact contract-off fp32 distance math -> argmax matches NumPy bit-for-bit;
// ties -> smallest index (prefer-left walk-down + (8191-idx) key low word).
// ---------------------------------------------------------------------------
__device__ __forceinline__ void producer(const KParams& P, char* smem, int b,
                                         int t, int lane, int w) {
#pragma clang fp contract(off)
  float4* s_xyz4 = (float4*)smem;                       // 128 KB
  float* s_ctr = (float*)(smem + 131072);               // 12 KB
  unsigned long long(*s_red)[4] =
      (unsigned long long(*)[4])(smem + 131072 + 12288);
  const float* base = P.xyz + (size_t)b * N * 3;
  v2f X[16], Y[16], Z[16], D[16];
  const int p0 = t * 32;
  {
    // 32 pts * 3 floats = 24 float4 loads, 16B-aligned (t*384 bytes);
    // mirrored float4-strided into LDS for 1-instr winner-coord broadcast.
    const float4* src = (const float4*)(base + (size_t)p0 * 3);
    float buf[96];
#pragma unroll
    for (int i = 0; i < 24; ++i) {
      float4 v = src[i];
      buf[4 * i + 0] = v.x; buf[4 * i + 1] = v.y;
      buf[4 * i + 2] = v.z; buf[4 * i + 3] = v.w;
    }
#pragma unroll
    for (int k = 0; k < 32; ++k)
      s_xyz4[p0 + k] =
          make_float4(buf[3 * k], buf[3 * k + 1], buf[3 * k + 2], 0.f);
#pragma unroll
    for (int i = 0; i < 16; ++i) {
      X[i] = (v2f){buf[6 * i + 0], buf[6 * i + 3]};
      Y[i] = (v2f){buf[6 * i + 1], buf[6 * i + 4]};
      Z[i] = (v2f){buf[6 * i + 2], buf[6 * i + 5]};
      D[i] = (v2f){3.4e38f, 3.4e38f};  // ref init +inf; min(inf,d)=d, d<=3
    }
  }
  float lx = base[0], ly = base[1], lz = base[2];  // start index 0
  if (t == 0) { s_ctr[0] = lx; s_ctr[1] = ly; s_ctr[2] = lz; }
  for (int r = 1; r < S; ++r) {
    v2f lx2 = lx, ly2 = ly, lz2 = lz;
    // exact: d = ((dx*dx)+(dy*dy))+(dz*dz), contraction off; pk ops round
    // identically to scalar per lane-half.
#pragma unroll
    for (int i = 0; i < 16; ++i) {
      v2f dx = X[i] - lx2, dy = Y[i] - ly2, dz = Z[i] - lz2;
      v2f d = (dx * dx + dy * dy) + dz * dz;
      D[i] = __builtin_elementwise_min(D[i], d);
    }
    // local max tree over 32 halves; prefer-left walk-down == first index
    float n1[16], n2[8], n3[4], n4[2];
#pragma unroll
    for (int i = 0; i < 16; ++i) n1[i] = fmaxf(D[i].x, D[i].y);
#pragma unroll
    for (int i = 0; i < 8; ++i) n2[i] = fmaxf(n1[2 * i], n1[2 * i + 1]);
#pragma unroll
    for (int i = 0; i < 4; ++i) n3[i] = fmaxf(n2[2 * i], n2[2 * i + 1]);
    n4[0] = fmaxf(n3[0], n3[1]);
    n4[1] = fmaxf(n3[2], n3[3]);
    float m = fmaxf(n4[0], n4[1]);
    int c4 = (n4[0] < m) ? 1 : 0;
    float n3s = c4 ? n3[2] : n3[0];
    int c3 = (n3s < m) ? 1 : 0;
    float n2a = c4 ? n2[4] : n2[0];
    float n2b = c4 ? n2[6] : n2[2];
    float n2s = c3 ? n2b : n2a;
    int c2 = (n2s < m) ? 1 : 0;
    float n1a = c4 ? n1[8] : n1[0];
    float n1b = c4 ? n1[10] : n1[2];
    float n1c = c4 ? n1[12] : n1[4];
    float n1d = c4 ? n1[14] : n1[6];
    float n1e = c3 ? n1c : n1a;
    float n1f = c3 ? n1d : n1b;
    float n1s = c2 ? n1f : n1e;
    int c1 = (n1s < m) ? 1 : 0;
    float e0 = c4 ? D[8].x : D[0].x;
    float e1 = c4 ? D[9].x : D[1].x;
    float e2 = c4 ? D[10].x : D[2].x;
    float e3 = c4 ? D[11].x : D[3].x;
    float e4 = c4 ? D[12].x : D[4].x;
    float e5 = c4 ? D[13].x : D[5].x;
    float e6 = c4 ? D[14].x : D[6].x;
    float e7 = c4 ? D[15].x : D[7].x;
    float f0 = c3 ? e4 : e0;
    float f1 = c3 ? e5 : e1;
    float f2 = c3 ? e6 : e2;
    float f3 = c3 ? e7 : e3;
    float g0 = c2 ? f2 : f0;
    float g1 = c2 ? f3 : f1;
    float dxs = c1 ? g1 : g0;
    int c0 = (dxs < m) ? 1 : 0;
    int li = 16 * c4 + 8 * c3 + 4 * c2 + 2 * c1 + c0;
    // wave max via DPP; index recovery via ballot (lane order == index order)
    float wm = wave_max_to_lane63(m);
    float wavemax =
        __int_as_float(__builtin_amdgcn_readlane(__float_as_int(wm), 63));
    unsigned long long bal = __ballot(m == wavemax);
    int firstlane = (int)__builtin_ctzll(bal);
    int widx = __builtin_amdgcn_readlane(p0 + li, firstlane);
    unsigned long long key =
        ((unsigned long long)__float_as_uint(wavemax) << 32) |
        (unsigned)(8191 - widx);
    if (lane == 0) s_red[r & 1][w] = key;
    __syncthreads();
    {  // parallel cross-wave reduce: 4 broadcast LDS reads + u64 max tree
      const unsigned long long* sr = s_red[r & 1];
      unsigned long long k0 = sr[0], k1 = sr[1], k2 = sr[2], k3 = sr[3];
      unsigned long long a = k0 > k1 ? k0 : k1;
      unsigned long long c = k2 > k3 ? k2 : k3;
      unsigned long long kmax = a > c ? a : c;
      const int bi = 8191 - (int)(unsigned)(kmax & 0xffffffffull);
      float4 cc = s_xyz4[bi];  // ONE ds_read_b128, broadcast
      lx = cc.x; ly = cc.y; lz = cc.z;
    }
    if (t == 0) {
      s_ctr[r * 3 + 0] = lx; s_ctr[r * 3 + 1] = ly; s_ctr[r * 3 + 2] = lz;
    }
    // Lagged publish: release prog for chunk k-1 (its stores drained 8
    // rounds ago -> vmcnt(0) instant), then relaxed-store chunk k's coords.
    if (w == 0 && (r & 7) == 7) {
      int k8 = r >> 3;
      if (lane == 0 && k8 >= 1)
        __hip_atomic_store(&P.prog[b * 64], (unsigned)(k8 * 8),
                           __ATOMIC_RELEASE, __HIP_MEMORY_SCOPE_AGENT);
      int cbase = (r - 7) * 3;
      if (lane < 24)
        __hip_atomic_store(P.ctrs + (size_t)b * (S * 3) + cbase + lane,
                           s_ctr[cbase + lane], __ATOMIC_RELAXED,
                           __HIP_MEMORY_SCOPE_AGENT);
    }
  }
  __syncthreads();
  if (w == 0 && lane == 0)  // final release covers the last 2 chunks
    __hip_atomic_store(&P.prog[b * 64], (unsigned)S, __ATOMIC_RELEASE,
                       __HIP_MEMORY_SCOPE_AGENT);
  float* o = P.new_xyz + (size_t)b * S * 3;
  for (int i = t; i < (S * 3) / 4; i += THREADS)
    ((float4*)o)[i] = ((const float4*)s_ctr)[i];
}

// ---------------------------------------------------------------------------
// Consumer: one wave per center (4 waves/block). Spin (s_sleep backoff) until
// the producer publishes center (b,s); ball query fused with coord gather;
// 3-layer BN-folded MLP + max. No block barriers (same-wave LDS RAW only).
// ---------------------------------------------------------------------------
__device__ __forceinline__ void consumer(const KParams& P, char* smem, int cid,
                                         int t, int lane, int w) {
#pragma clang fp contract(off)
  constexpr float R2 = (float)(0.2 * 0.2);
  float* h = (float*)smem + w * (NS * 64);              // 8 KB per wave
  float* cs = (float*)smem + 4 * NS * 64 + w * (NS * 4);
  const unsigned gw = cid * 4 + w;  // global consumer wave id, 0..991
  // BN-folded weights, loaded once per wave (registers)
  float sv1 = P.g1[lane] / sqrtf(P.v1[lane] + BN_EPS);
  float bb1 = (P.b1[lane] - P.m1[lane]) * sv1 + P.be1[lane];
  float w1x = P.w1[lane * 3 + 0] * sv1, w1y = P.w1[lane * 3 + 1] * sv1,
        w1z = P.w1[lane * 3 + 2] * sv1;
  float sv2 = P.g2[lane] / sqrtf(P.v2[lane] + BN_EPS);
  float bb2 = (P.b2[lane] - P.m2[lane]) * sv2 + P.be2[lane];
  float W2[64];
#pragma unroll
  for (int k = 0; k < 64; k += 4) {
    float4 q = *(const float4*)(P.w2 + lane * 64 + k);
    W2[k + 0] = q.x * sv2; W2[k + 1] = q.y * sv2;
    W2[k + 2] = q.z * sv2; W2[k + 3] = q.w * sv2;
  }
  float sva = P.g3[lane] / sqrtf(P.v3[lane] + BN_EPS);
  float bba = (P.b3[lane] - P.m3[lane]) * sva + P.be3[lane];
  float svb = P.g3[lane + 64] / sqrtf(P.v3[lane + 64] + BN_EPS);
  float bbb = (P.b3[lane + 64] - P.m3[lane + 64]) * svb + P.be3[lane + 64];
  float Wa[64], Wb[64];
#pragma unroll
  for (int k = 0; k < 64; k += 4) {
    float4 qa = *(const float4*)(P.w3 + lane * 64 + k);
    Wa[k + 0] = qa.x * sva; Wa[k + 1] = qa.y * sva;
    Wa[k + 2] = qa.z * sva; Wa[k + 3] = qa.w * sva;
    float4 qb = *(const float4*)(P.w3 + (lane + 64) * 64 + k);
    Wb[k + 0] = qb.x * svb; Wb[k + 1] = qb.y * svb;
    Wb[k + 2] = qb.z * svb; Wb[k + 3] = qb.w * svb;
  }
  for (unsigned c = gw; c < B * S; c += NCONS_WAVE) {
    const int b = c & 7;
    const int s = c >> 3;
    while (__hip_atomic_load(&P.prog[b * 64], __ATOMIC_RELAXED,
                             __HIP_MEMORY_SCOPE_AGENT) <= (unsigned)s)
      __builtin_amdgcn_s_sleep(8);
    (void)__hip_atomic_load(&P.prog[b * 64], __ATOMIC_ACQUIRE,
                            __HIP_MEMORY_SCOPE_AGENT);
    const float* cg = P.ctrs + (size_t)b * (S * 3) + s * 3;
    float cx = __hip_atomic_load(cg + 0, __ATOMIC_RELAXED,
                                 __HIP_MEMORY_SCOPE_AGENT);
    float cy = __hip_atomic_load(cg + 1, __ATOMIC_RELAXED,
                                 __HIP_MEMORY_SCOPE_AGENT);
    float cz = __hip_atomic_load(cg + 2, __ATOMIC_RELAXED,
                                 __HIP_MEMORY_SCOPE_AGENT);
    const float* base = P.xyz + (size_t)b * N * 3;
    // ball query fused with coord gather: finder lane scatters coords to cs
    int cnt = 0;
    for (int c0 = 0; c0 < N && cnt < NS; c0 += 64) {
      int p = c0 + lane;
      float x = base[p * 3], y = base[p * 3 + 1], z = base[p * 3 + 2];
      float dx = x - cx, dy = y - cy, dz = z - cz;
      float d = (dx * dx + dy * dy) + dz * dz;
      bool v = d < R2;  // strict <, exact fp32: matches reference
      unsigned long long mk = __ballot(v);
      int rank = cnt + __popcll(mk & ((1ull << lane) - 1ull));
      if (v && rank < NS) {
        cs[rank * 4 + 0] = x; cs[rank * 4 + 1] = y; cs[rank * 4 + 2] = z;
      }
      cnt += (int)__popcll(mk);
    }
    if (cnt < NS) {  // pad -> point 0 coords (pytorch3d clamp semantics)
      float x0 = base[0], y0 = base[1], z0 = base[2];
      for (int j = cnt + lane; j < NS; j += 64) {
        cs[j * 4 + 0] = x0; cs[j * 4 + 1] = y0; cs[j * 4 + 2] = z0;
      }
    }
    // layer 1: 3 -> 64
    for (int n = 0; n < NS; ++n) {
      float a = fmaf(w1x, cs[n * 4 + 0],
                     fmaf(w1y, cs[n * 4 + 1], fmaf(w1z, cs[n * 4 + 2], bb1)));
      h[n * 64 + lane] = fmaxf(a, 0.f);
    }
    // layer 2: 64 -> 64 (in-place row overwrite, wave-lockstep safe)
    for (int n = 0; n < NS; ++n) {
      float acc = bb2;
#pragma unroll
      for (int k = 0; k < 64; k += 4) {
        float4 q = *(const float4*)(h + n * 64 + k);
        acc = fmaf(W2[k + 0], q.x, acc);
        acc = fmaf(W2[k + 1], q.y, acc);
        acc = fmaf(W2[k + 2], q.z, acc);
        acc = fmaf(W2[k + 3], q.w, acc);
      }
      h[n * 64 + lane] = fmaxf(acc, 0.f);
    }
    // layer 3: 64 -> 128, both halves per pass, fused max over samples
    float mxa = 0.f, mxb = 0.f;
    for (int n = 0; n < NS; ++n) {
      float acca = bba, accb = bbb;
#pragma unroll
      for (int k = 0; k < 64; k += 4) {
        float4 q = *(const float4*)(h + n * 64 + k);
        acca = fmaf(Wa[k + 0], q.x, acca);
        acca = fmaf(Wa[k + 1], q.y, acca);
        acca = fmaf(Wa[k + 2], q.z, acca);
        acca = fmaf(Wa[k + 3], q.w, acca);
        accb = fmaf(Wb[k + 0], q.x, accb);
        accb = fmaf(Wb[k + 1], q.y, accb);
        accb = fmaf(Wb[k + 2], q.z, accb);
        accb = fmaf(Wb[k + 3], q.w, accb);
      }
      mxa = fmaxf(mxa, acca);
      mxb = fmaxf(mxb, accb);
    }
    P.out_feat[((size_t)b * 128 + lane) * S + s] = mxa;
    P.out_feat[((size_t)b * 128 + 64 + lane) * S + s] = mxb;
  }
}

// ---------------------------------------------------------------------------
__global__ void __attribute__((amdgpu_flat_work_group_size(THREADS, THREADS),
                               amdgpu_waves_per_eu(2, 2)))
k_fused(KParams P) {
  extern __shared__ char smem[];
  const int t = threadIdx.x;
  const int lane = t & 63;
  const int w = t >> 6;
  if (blockIdx.x < B)
    producer(P, smem, blockIdx.x, t, lane, w);
  else
    consumer(P, smem, blockIdx.x - B, t, lane, w);
}

// ---------------------------------------------------------------------------
extern "C" void kernel_launch(void* const* d_in, const int* in_sizes, int n_in,
                              void* d_out, int out_size, void* d_ws,
                              size_t ws_size, hipStream_t stream) {
  KParams P;
  P.xyz = (const float*)d_in[0];
  P.w1 = (const float*)d_in[1];  P.b1 = (const float*)d_in[2];
  P.g1 = (const float*)d_in[3];  P.be1 = (const float*)d_in[4];
  P.m1 = (const float*)d_in[5];  P.v1 = (const float*)d_in[6];
  P.w2 = (const float*)d_in[7];  P.b2 = (const float*)d_in[8];
  P.g2 = (const float*)d_in[9];  P.be2 = (const float*)d_in[10];
  P.m2 = (const float*)d_in[11]; P.v2 = (const float*)d_in[12];
  P.w3 = (const float*)d_in[13]; P.b3 = (const float*)d_in[14];
  P.g3 = (const float*)d_in[15]; P.be3 = (const float*)d_in[16];
  P.m3 = (const float*)d_in[17]; P.v3 = (const float*)d_in[18];
  float* out = (float*)d_out;
  P.new_xyz = out;
  P.out_feat = out + (size_t)B * S * 3;
  P.prog = (unsigned*)d_ws;                       // 8 x 64 u32 = 2 KB
  P.ctrs = (float*)((char*)d_ws + 2048);          // 96 KB

  // d_ws is re-poisoned to 0xAA before every timed launch: zero the progress
  // counters (async, graph-capturable) or consumers would see garbage.
  hipMemsetAsync(d_ws, 0, 2048, stream);

  void* args[] = {&P};
  dim3 grid(B + NCONS_BLK), blk(THREADS);
  size_t shmem = 131072 + 12288 + 256;  // producer overlay is the max
  hipError_t e = hipLaunchCooperativeKernel((const void*)k_fused, grid, blk,
                                            args, (unsigned)shmem, stream);
  if (e != hipSuccess) {
    // Fallback: plain launch of the same kernel. 256 blocks x 140KB LDS =
    // 1 block/CU on 256 CUs -> de-facto co-resident.
    k_fused<<<grid, blk, shmem, stream>>>(P);
  }
}